// Round 10
// baseline (693.461 us; speedup 1.0000x reference)
//
#include <hip/hip_runtime.h>

// Batched Hungarian matcher — TRAJECTORY-EXACT Jonker-Volgenant replication
// of the numpy reference (zero initial duals, rows in order, exact f64 on
// exact f32 costs, lowest-index tie-breaks). Semantics identical to the
// proven R2 kernel (absmax 0); R10 trims the per-round serial chain:
//  - v duals live in REGISTERS (8 f64/thread, owner-updated at row end with
//    the exact same f64 arithmetic) => no per-round LDS v loads.
//  - FAT SLOTS: wave leaders pre-resolve the winner metadata BEFORE the
//    barrier (row4col[bj], uu/tx/tch of that row) and publish it with their
//    reduction slot => the dependent post-barrier LDS chain (row4col ->
//    row data, ~250 cyc) is gone; all threads merge 8 fat slots and start
//    the next relax immediately.
//  - one barrier per round (parity-buffered slots), static-only register
//    indexing (no scratch spills).

#define Bb 32
#define Nn 4096
#define Mm 128
#define Tt 512
#define Kk (Nn / Tt)   // 8 columns per thread
#define TSH 9          // log2(Tt)
#define NW (Tt / 64)   // 8 waves
#define RECMAX 136

__global__ __launch_bounds__(Tt, 1)
void hungarian_kernel(const float* __restrict__ predict_scores,
                      const float* __restrict__ predict_points,
                      const int*   __restrict__ scores,
                      const float* __restrict__ points,
                      int* __restrict__ out)
{
    __shared__ short  path_lds[Nn];      // predecessor row per column
    __shared__ short  row4col[Nn];       // matched row per column (-1 free)
    __shared__ double uu[Mm];            // row duals (exact f64)
    __shared__ short  col4row[Mm];       // matched column per row (-1 free)
    __shared__ double srow_val[Mm];      // minv when row was scanned
    __shared__ unsigned char SRr[Mm];    // scanned-row flags
    __shared__ float  tx0[Mm], tx1[Mm];
    __shared__ int    tch[Mm];
    __shared__ short  pcol[RECMAX];      // popped columns (this search)
    __shared__ double pval[RECMAX];      // their exact pop values
    // parity-buffered FAT reduction slots (one per wave)
    __shared__ double slotVal[2][NW];    // candidate shortest value
    __shared__ int    slotMeta[2][NW];   // j | ch<<12 | (r4+1)<<16
    __shared__ double slotU[2][NW];      // uu[r4] (pre-resolved)
    __shared__ float  slotT0[2][NW], slotT1[2][NW];

    const int b   = blockIdx.x;
    const int tid = threadIdx.x;
    const double INFD = __builtin_inf();

    // ---- per-column data -> registers ----
    float negp0[Kk], negp1[Kk], qx0[Kk], qx1[Kk];
    double v64[Kk];                      // column duals, register-resident
    const float* ps = predict_scores + (size_t)b * Nn * 2;
    const float* pp = predict_points + (size_t)b * Nn * 2;
    #pragma unroll
    for (int k = 0; k < Kk; ++k) {
        int j = tid + (k << TSH);
        float2 sc = ((const float2*)ps)[j];
        float mx = fmaxf(sc.x, sc.y);
        float e0 = expf(sc.x - mx), e1 = expf(sc.y - mx);
        float sm = e0 + e1;
        negp0[k] = -(e0 / sm);
        negp1[k] = -(e1 / sm);
        float2 qp = ((const float2*)pp)[j];
        qx0[k] = qp.x; qx1[k] = qp.y;
        v64[k] = 0.0;
        row4col[j] = -1;
    }
    if (tid < Mm) {
        uu[tid] = 0.0;
        col4row[tid] = -1;
        SRr[tid] = 0;
        tx0[tid] = points[(size_t)b * Mm * 2 + 2 * tid];
        tx1[tid] = points[(size_t)b * Mm * 2 + 2 * tid + 1];
        tch[tid] = scores[(size_t)b * Mm + tid];
    }
    __syncthreads();

    // ---- JV outer loop over rows (targets) ----
    for (int cur_row = 0; cur_row < Mm; ++cur_row) {
        double shr[Kk];
        #pragma unroll
        for (int k = 0; k < Kk; ++k) shr[k] = INFD;
        unsigned scm = 0;                // scanned-column bits (this thread)
        int    i    = cur_row;
        double minv = 0.0;
        int    sink = -1, par = 0, Spop = 0;
        // current scan-row data (uniform registers)
        double ui = uu[cur_row];
        float  t0 = tx0[cur_row], t1 = tx1[cur_row];
        int    ch = tch[cur_row];

        for (;;) {
            // ---- relax row i over this thread's 8 columns (exact f64) ----
            double bv = INFD; int bj = Nn;
            #pragma unroll
            for (int k = 0; k < Kk; ++k) {
                int j = tid + (k << TSH);
                if (!((scm >> k) & 1u)) {
                    float cf = ((ch == 1) ? negp1[k] : negp0[k])
                             + (fabsf(qx0[k] - t0) + fabsf(qx1[k] - t1));
                    double r = ((minv + (double)cf) - ui) - v64[k]; // numpy order
                    if (r < shr[k]) { shr[k] = r; path_lds[j] = (short)i; }
                    if (shr[k] < bv) { bv = shr[k]; bj = j; } // k asc => low j tie
                }
            }
            // ---- in-wave lex argmin ----
            #pragma unroll
            for (int off = 32; off > 0; off >>= 1) {
                double ov = __shfl_xor(bv, off);
                int    oj = __shfl_xor(bj, off);
                if (ov < bv || (ov == bv && oj < bj)) { bv = ov; bj = oj; }
            }
            // ---- leader pre-resolves candidate metadata (pre-barrier) ----
            if ((tid & 63) == 0) {
                int wv = tid >> 6;
                int r4 = (int)row4col[bj];
                double u2 = 0.0; float a0 = 0.0f, a1 = 0.0f; int c2 = 0;
                if (r4 >= 0) { u2 = uu[r4]; a0 = tx0[r4]; a1 = tx1[r4]; c2 = tch[r4]; }
                slotVal[par][wv]  = bv;
                slotMeta[par][wv] = bj | (c2 << 12) | ((r4 + 1) << 16);
                slotU[par][wv]    = u2;
                slotT0[par][wv]   = a0;
                slotT1[par][wv]   = a1;
            }
            __syncthreads();                       // the single barrier
            // ---- all threads merge the 8 fat slots ----
            double best = slotVal[par][0]; int bm = slotMeta[par][0];
            double bu = slotU[par][0]; float b0 = slotT0[par][0], b1 = slotT1[par][0];
            #pragma unroll
            for (int w = 1; w < NW; ++w) {
                double ov = slotVal[par][w]; int om = slotMeta[par][w];
                bool take = (ov < best) ||
                            (ov == best && (om & 4095) < (bm & 4095));
                if (take) {
                    best = ov; bm = om;
                    bu = slotU[par][w]; b0 = slotT0[par][w]; b1 = slotT1[par][w];
                }
            }
            par ^= 1;
            minv = best;
            const int bestj = bm & 4095;
            const int r4    = (bm >> 16) - 1;
            // owner excludes the popped column (static unroll, no spills)
            #pragma unroll
            for (int k = 0; k < Kk; ++k)
                if (bestj == tid + (k << TSH)) scm |= 1u << k;
            if (tid == 0) { pcol[Spop] = (short)bestj; pval[Spop] = best; }
            Spop++;
            if (r4 < 0) { sink = bestj; break; }   // uniform exit
            if (tid == 0) { SRr[r4] = 1; srow_val[r4] = best; }
            i = r4; ui = bu; t0 = b0; t1 = b1; ch = (bm >> 12) & 1;
        }
        __syncthreads();                           // publish pops/SRr/path

        // ---- row end: exact dual updates + augment ----
        const double mF = minv;
        if (tid < Mm) {
            if (tid == cur_row)   uu[tid] += mF;
            else if (SRr[tid]) {  uu[tid] += mF - srow_val[tid]; SRr[tid] = 0; }
        }
        for (int e = 0; e < Spop; ++e) {           // broadcast reads; owner updates
            int c = (int)pcol[e];
            double pv = pval[e];
            #pragma unroll
            for (int k = 0; k < Kk; ++k)
                if (c == tid + (k << TSH)) v64[k] -= (mF - pv); // sink: -0, no-op
        }
        if (tid == 0) {
            int j = sink;
            for (;;) {
                int i2 = (int)path_lds[j];
                row4col[j] = (short)i2;
                int nxt = (int)col4row[i2];
                col4row[i2] = (short)j;
                j = nxt;
                if (i2 == cur_row) break;
            }
        }
        __syncthreads();
    }

    // ---- emit (batch, src sorted ascending, tgt) ----
    if (tid < Mm) {
        int myj = (int)col4row[tid];
        int rank = 0;
        #pragma unroll 4
        for (int t = 0; t < Mm; ++t) rank += ((int)col4row[t] < myj) ? 1 : 0;
        out[b * Mm + tid] = b;                     // batch_idx
        out[Bb * Mm + b * Mm + rank] = myj;        // src_idx (sorted)
        out[2 * Bb * Mm + b * Mm + rank] = tid;    // tgt_idx
    }
}

extern "C" void kernel_launch(void* const* d_in, const int* in_sizes, int n_in,
                              void* d_out, int out_size, void* d_ws, size_t ws_size,
                              hipStream_t stream) {
    (void)in_sizes; (void)n_in; (void)d_ws; (void)ws_size; (void)out_size;
    const float* predict_scores = (const float*)d_in[0];
    const float* predict_points = (const float*)d_in[1];
    const int*   scores         = (const int*)d_in[2];
    const float* points         = (const float*)d_in[3];
    int* out = (int*)d_out;
    hipLaunchKernelGGL(hungarian_kernel, dim3(Bb), dim3(Tt), 0, stream,
                       predict_scores, predict_points, scores, points, out);
}

// Round 11
// 632.865 us; speedup vs baseline: 1.0957x; 1.0957x over previous
//
#include <hip/hip_runtime.h>

// Batched Hungarian matcher — TRAJECTORY-EXACT Jonker-Volgenant replication
// of the numpy reference (zero initial duals, rows in order, exact f64 on
// exact f32 costs, lowest-index tie-breaks). Based on the proven R5 kernel
// (f32 packed relax + rigorous Dmax certification + uniform exact resolve,
// absmax 0). R11 cuts the per-round serial chain:
//  - U64-PACKED SLOTS: wave leaders pre-resolve row4col[bj] BEFORE the
//    barrier (absorbed into arrival skew) and publish one u64 key =
//    sortable(m1)<<20 | j<<8 | (r4+1), plus a 16B side-slot {u,t0,t1}
//    and {m2,ch}. Post-barrier: 8 independent b128 reads + u64 lex-min —
//    the old merge -> row4col -> row-data dependent LDS chain is gone.
//  - records packed 32B/entry (2 x b128 per resolve iteration).
//  - record appends use slot-carried registers (no LDS reads).

typedef float v2f __attribute__((ext_vector_type(2)));

#define Bb 32
#define Nn 4096
#define Mm 128
#define Tt 256
#define KP 8           // v2f pairs per thread (16 cols)
#define RECMAX 136

static __device__ inline v2f vabs2(v2f x) {
    v2f r; r.x = __builtin_fabsf(x.x); r.y = __builtin_fabsf(x.y); return r;
}
static __device__ inline v2f vmin2(v2f a, v2f b) {
    v2f r; r.x = fminf(a.x, b.x); r.y = fminf(a.y, b.y); return r;
}
// strictly monotone float -> u32 (total order preserved, inf sorts high)
static __device__ inline unsigned sortK(float f) {
    unsigned u = __float_as_uint(f);
    return u ^ (unsigned)(((int)u >> 31) | 0x80000000);
}
static __device__ inline float unsortK(unsigned s) {
    unsigned u = (s & 0x80000000u) ? (s ^ 0x80000000u) : ~s;
    return __uint_as_float(u);
}

__global__ __launch_bounds__(Tt, 1)
void hungarian_kernel(const float* __restrict__ predict_scores,
                      const float* __restrict__ predict_points,
                      const int*   __restrict__ scores,
                      const float* __restrict__ points,
                      int* __restrict__ out)
{
    __shared__ double vvl[Nn];            // column duals (exact f64)
    __shared__ float  pn0l[Nn], pn1l[Nn]; // -softmax probs (exact f32)
    __shared__ float2 qxl[Nn];            // prediction points
    __shared__ short  path_lds[Nn];       // predecessor (written at pops)
    __shared__ short  row4col[Nn];        // matched row per col (-1 free)
    __shared__ double uu[Mm];             // row duals
    __shared__ short  col4row[Mm];
    __shared__ double srow_val[Mm];       // minv when row scanned
    __shared__ unsigned char SRr[Mm];
    __shared__ float4 rowdat[Mm];         // {t0, t1, ch_as_float, 0}
    __shared__ double recMU[2 * RECMAX];  // [2s]=minv, [2s+1]=u (b128 pair)
    __shared__ float4 recT[RECMAX];       // {t0, t1, ch, row_as_float}
    __shared__ short  pcol[RECMAX];
    __shared__ double pval[RECMAX];
    __shared__ uint4  slotA[2][4];        // {keyLo, keyHi, m2sort, ch}
    __shared__ uint4  slotB[2][4];        // {uLo, uHi, t0bits, t1bits}
    __shared__ uint4  fred[2][4];         // fallback: {bvLo, bvHi, j, pred}

    const int b   = blockIdx.x;
    const int tid = threadIdx.x;
    const double INFD = __builtin_inf();
    const float  INFF = __builtin_inff();

    // ---------------- setup ----------------
    v2f negp0v[KP], negp1v[KP], qx0v[KP], qx1v[KP], v32v[KP], shrv[KP];
    const float* ps = predict_scores + (size_t)b * Nn * 2;
    const float* pp = predict_points + (size_t)b * Nn * 2;
    #pragma unroll
    for (int p2 = 0; p2 < KP; ++p2) {
        #pragma unroll
        for (int e = 0; e < 2; ++e) {
            int j = tid + ((2 * p2 + e) << 8);
            float2 sc = ((const float2*)ps)[j];
            float mx = fmaxf(sc.x, sc.y);
            float e0 = expf(sc.x - mx), e1 = expf(sc.y - mx);
            float sm = e0 + e1;
            float n0 = -(e0 / sm), n1 = -(e1 / sm);
            float2 qp = ((const float2*)pp)[j];
            if (e == 0) {
                negp0v[p2].x = n0; negp1v[p2].x = n1;
                qx0v[p2].x = qp.x; qx1v[p2].x = qp.y; v32v[p2].x = 0.0f;
            } else {
                negp0v[p2].y = n0; negp1v[p2].y = n1;
                qx0v[p2].y = qp.x; qx1v[p2].y = qp.y; v32v[p2].y = 0.0f;
            }
            pn0l[j] = n0; pn1l[j] = n1;
            qxl[j] = qp;
            vvl[j] = 0.0;
            row4col[j] = -1;
        }
    }
    if (tid < Mm) {
        uu[tid] = 0.0; col4row[tid] = -1; SRr[tid] = 0;
        float t0 = points[(size_t)b * Mm * 2 + 2 * tid];
        float t1 = points[(size_t)b * Mm * 2 + 2 * tid + 1];
        int   ch = scores[(size_t)b * Mm + tid];
        rowdat[tid] = make_float4(t0, t1, (float)ch, 0.0f);
    }
    __syncthreads();

    float Vcap = 0.0f;
    int par = 0;

    // ---------------- JV outer loop ----------------
    for (int cur_row = 0; cur_row < Mm; ++cur_row) {
        #pragma unroll
        for (int p2 = 0; p2 < KP; ++p2) { shrv[p2].x = INFF; shrv[p2].y = INFF; }
        int    Srow = 1, Spop = 0, sink = -1;
        double minv = 0.0;
        float  Dmax = 0.0f;
        double ui;
        float  t0, t1;
        bool   chIs1;
        {
            float4 rd0 = rowdat[cur_row];
            ui = uu[cur_row];
            t0 = rd0.x; t1 = rd0.y; chIs1 = (rd0.z != 0.0f);
            if (tid == 0) {
                recMU[0] = 0.0; recMU[1] = ui;
                recT[0] = make_float4(t0, t1, rd0.z, (float)cur_row);
            }
        }

        for (int pops = 0; pops < RECMAX - 4; ++pops) {
            // ---- f32 packed relax (registers only) ----
            const float base32 = (float)(minv - ui);
            float delta = 3e-6f * (fabsf((float)minv) + fabsf((float)ui) + 4.0f + Vcap);
            Dmax = fmaxf(Dmax, delta);
            v2f basev; basev.x = base32; basev.y = base32;
            v2f t0v; t0v.x = t0; t0v.y = t0;
            v2f t1v; t1v.x = t1; t1v.y = t1;
            #pragma unroll
            for (int p2 = 0; p2 < KP; ++p2) {
                v2f pres = chIs1 ? negp1v[p2] : negp0v[p2];
                v2f l1 = vabs2(qx0v[p2] - t0v) + vabs2(qx1v[p2] - t1v);
                v2f r = (basev + (pres + l1)) - v32v[p2];
                shrv[p2] = vmin2(shrv[p2], r);
            }
            // ---- per-thread (m1, j, m2) ----
            float m1 = INFF, m2 = INFF; int j1i = Nn;
            #pragma unroll
            for (int p2 = 0; p2 < KP; ++p2) {
                #pragma unroll
                for (int e = 0; e < 2; ++e) {
                    float val = (e == 0) ? shrv[p2].x : shrv[p2].y;
                    int j = tid + ((2 * p2 + e) << 8);
                    bool lt1 = val < m1;
                    float old1 = m1;
                    m1 = lt1 ? val : m1;
                    j1i = lt1 ? j : j1i;
                    m2 = fminf(m2, lt1 ? old1 : val);
                }
            }
            // ---- wave reduce (lex m1, carry m2) ----
            #pragma unroll
            for (int off = 32; off > 0; off >>= 1) {
                float om1 = __shfl_xor(m1, off);
                int   oj  = __shfl_xor(j1i, off);
                float om2 = __shfl_xor(m2, off);
                float big = fmaxf(m1, om1);
                m2 = fminf(fminf(m2, om2), big);
                bool take = (om1 < m1) || (om1 == m1 && oj < j1i);
                m1 = take ? om1 : m1;
                j1i = take ? oj : j1i;
            }
            // ---- leader: pre-resolve r4 + row data, publish packed slot ----
            if ((tid & 63) == 0) {
                int wv = tid >> 6;
                int jw = (j1i < Nn) ? j1i : 0;
                int r4 = (int)row4col[jw];
                unsigned s1 = sortK(m1);
                unsigned long long key =
                    ((unsigned long long)s1 << 20) |
                    ((unsigned long long)(unsigned)jw << 8) |
                    (unsigned long long)(unsigned)(r4 + 1);
                double u2 = 0.0;
                float4 rd = make_float4(0.f, 0.f, 0.f, 0.f);
                if (r4 >= 0) { u2 = uu[r4]; rd = rowdat[r4]; }
                unsigned long long ub = (unsigned long long)__double_as_longlong(u2);
                slotA[par][wv] = make_uint4((unsigned)key, (unsigned)(key >> 32),
                                            sortK(m2), __float_as_uint(rd.z));
                slotB[par][wv] = make_uint4((unsigned)(ub & 0xffffffffull),
                                            (unsigned)(ub >> 32),
                                            __float_as_uint(rd.x), __float_as_uint(rd.y));
            }
            __syncthreads();                               // THE barrier
            const int rp = par; par ^= 1;
            // ---- merge 4 packed slots (independent b128 reads) ----
            uint4 a0 = slotA[rp][0], b0 = slotB[rp][0];
            unsigned long long best =
                ((unsigned long long)a0.y << 32) | a0.x;
            unsigned m2s = a0.z;
            uint4 bA = a0, bB = b0;
            #pragma unroll
            for (int w = 1; w < 4; ++w) {
                uint4 aw = slotA[rp][w], bw = slotB[rp][w];
                unsigned long long k = ((unsigned long long)aw.y << 32) | aw.x;
                bool take = k < best;
                unsigned loserVal = take ? (unsigned)(best >> 20) : (unsigned)(k >> 20);
                unsigned mm = aw.z < loserVal ? aw.z : loserVal;
                m2s = mm < m2s ? mm : m2s;
                if (take) { best = k; bA = aw; bB = bw; }
            }
            int   jstar = (int)((best >> 8) & 0xFFFull);
            int   r4v   = (int)(best & 0xFFull) - 1;
            float m1g   = unsortK((unsigned)(best >> 20));
            float m2g   = unsortK(m2s);

            const bool certified = (m2g - m1g) > (2.0f * Dmax);
            double minvN; int pred;
            double un; float t0n, t1n; int chn;
            if (certified) {
                // ---- uniform exact resolve of j* (f64, numpy op order) ----
                double vj = vvl[jstar];
                float c0 = pn0l[jstar], c1 = pn1l[jstar];
                float2 qp = qxl[jstar];
                double sv = INFD; int pr = -1;
                for (int s = 0; s < Srow; ++s) {
                    double pm = recMU[2 * s], pu = recMU[2 * s + 1];
                    float4 rt = recT[s];
                    float cf = ((rt.z != 0.0f) ? c1 : c0)
                             + fabsf(qp.x - rt.x) + fabsf(qp.y - rt.y);
                    double r = ((pm + (double)cf) - pu) - vj;
                    if (r < sv) { sv = r; pr = (int)rt.w; }
                }
                minvN = sv; pred = pr;
                // next-row data from slot registers (no LDS chain)
                un  = __longlong_as_double(
                        (long long)(((unsigned long long)bB.y << 32) | bB.x));
                t0n = __uint_as_float(bB.z);
                t1n = __uint_as_float(bB.w);
                chn = (int)__uint_as_float(bA.w);
            } else {
                // ---- exact fallback: all contenders, extra barrier ----
                float cth = m1g + 2.0f * Dmax;
                double bv = INFD; int bj = Nn, bp = -1;
                #pragma unroll
                for (int p2 = 0; p2 < KP; ++p2) {
                    #pragma unroll
                    for (int e = 0; e < 2; ++e) {
                        float sval = (e == 0) ? shrv[p2].x : shrv[p2].y;
                        if (sval <= cth) {
                            int j = tid + ((2 * p2 + e) << 8);
                            double vj = vvl[j];
                            float c0 = (e == 0) ? negp0v[p2].x : negp0v[p2].y;
                            float c1 = (e == 0) ? negp1v[p2].x : negp1v[p2].y;
                            float qa = (e == 0) ? qx0v[p2].x : qx0v[p2].y;
                            float qb = (e == 0) ? qx1v[p2].x : qx1v[p2].y;
                            double sv = INFD; int pr = -1;
                            for (int s = 0; s < Srow; ++s) {
                                double pm = recMU[2 * s], pu = recMU[2 * s + 1];
                                float4 rt = recT[s];
                                float cf = ((rt.z != 0.0f) ? c1 : c0)
                                         + fabsf(qa - rt.x) + fabsf(qb - rt.y);
                                double r = ((pm + (double)cf) - pu) - vj;
                                if (r < sv) { sv = r; pr = (int)rt.w; }
                            }
                            if (sv < bv || (sv == bv && j < bj)) { bv = sv; bj = j; bp = pr; }
                        }
                    }
                }
                #pragma unroll
                for (int off = 32; off > 0; off >>= 1) {
                    double ov = __shfl_xor(bv, off);
                    int    oj = __shfl_xor(bj, off);
                    int    op = __shfl_xor(bp, off);
                    if (ov < bv || (ov == bv && oj < bj)) { bv = ov; bj = oj; bp = op; }
                }
                if ((tid & 63) == 0) {
                    unsigned long long bb = (unsigned long long)__double_as_longlong(bv);
                    fred[par][tid >> 6] = make_uint4((unsigned)(bb & 0xffffffffull),
                                                     (unsigned)(bb >> 32),
                                                     (unsigned)bj, (unsigned)bp);
                }
                __syncthreads();                           // extra barrier (rare)
                const int rp2 = par; par ^= 1;
                uint4 q = fred[rp2][0];
                double bg = __longlong_as_double(
                    (long long)(((unsigned long long)q.y << 32) | q.x));
                int jg = (int)q.z, pg = (int)q.w;
                #pragma unroll
                for (int w = 1; w < 4; ++w) {
                    uint4 r = fred[rp2][w];
                    double ov = __longlong_as_double(
                        (long long)(((unsigned long long)r.y << 32) | r.x));
                    int oj = (int)r.z;
                    if (ov < bg || (ov == bg && oj < jg)) { bg = ov; jg = oj; pg = (int)r.w; }
                }
                minvN = bg; jstar = jg; pred = pg;
                r4v = (int)row4col[jstar];
                un = 0.0; t0n = 0.0f; t1n = 0.0f; chn = 0;
                if (r4v >= 0) {
                    un = uu[r4v];
                    float4 rd = rowdat[r4v];
                    t0n = rd.x; t1n = rd.y; chn = (int)rd.z;
                }
            }

            // ---- uniform pop bookkeeping ----
            #pragma unroll
            for (int p2 = 0; p2 < KP; ++p2) {              // owner poison
                if (jstar == tid + ((2 * p2)     << 8)) { shrv[p2].x = INFF; v32v[p2].x = -1e30f; }
                if (jstar == tid + ((2 * p2 + 1) << 8)) { shrv[p2].y = INFF; v32v[p2].y = -1e30f; }
            }
            minv = minvN;
            if (tid == 0) {
                path_lds[jstar] = (short)pred;
                pcol[Spop] = (short)jstar; pval[Spop] = minv;
            }
            Spop++;
            if (r4v < 0) { sink = jstar; break; }          // uniform exit
            if (tid == 0) {
                SRr[r4v] = 1; srow_val[r4v] = minv;
                recMU[2 * Srow] = minv; recMU[2 * Srow + 1] = un;
                recT[Srow] = make_float4(t0n, t1n, (float)chn, (float)r4v);
            }
            Srow++;
            ui = un; t0 = t0n; t1 = t1n; chIs1 = (chn == 1);
        }
        __syncthreads();   // publish final pop's records

        // ---- row end: exact dual updates + augment ----
        const double minvF = minv;
        const int SpopL = Spop;
        if (tid < Mm) {
            if (tid == cur_row)   uu[tid] += minvF;
            else if (SRr[tid]) {  uu[tid] += minvF - srow_val[tid]; SRr[tid] = 0; }
        }
        for (int e = 0; e < SpopL; ++e) {
            int c = (int)pcol[e];
            if ((c & (Tt - 1)) == tid) vvl[c] -= (minvF - pval[e]);
        }
        Vcap += (float)(minvF - pval[0]) + 1e-6f;
        if (tid == 0 && sink >= 0) {
            int j = sink;
            for (;;) {
                int i2 = (int)path_lds[j];
                row4col[j] = (short)i2;
                int nxt = (int)col4row[i2];
                col4row[i2] = (short)j;
                j = nxt;
                if (i2 == cur_row) break;
            }
        }
        __syncthreads();
        // rebuild f32 v mirror from exact vvl (un-poisons popped cols)
        #pragma unroll
        for (int p2 = 0; p2 < KP; ++p2) {
            int j0  = tid + ((2 * p2) << 8);
            int j1c = tid + ((2 * p2 + 1) << 8);
            v32v[p2].x = (float)vvl[j0];
            v32v[p2].y = (float)vvl[j1c];
        }
    }

    // ---------------- emit ----------------
    if (tid < Mm) {
        int myj = (int)col4row[tid];
        int rank = 0;
        #pragma unroll 4
        for (int t = 0; t < Mm; ++t) rank += ((int)col4row[t] < myj) ? 1 : 0;
        out[b * Mm + tid] = b;                      // batch_idx
        out[Bb * Mm + b * Mm + rank] = myj;         // src_idx (sorted)
        out[2 * Bb * Mm + b * Mm + rank] = tid;     // tgt_idx
    }
}

extern "C" void kernel_launch(void* const* d_in, const int* in_sizes, int n_in,
                              void* d_out, int out_size, void* d_ws, size_t ws_size,
                              hipStream_t stream) {
    (void)in_sizes; (void)n_in; (void)d_ws; (void)ws_size; (void)out_size;
    const float* predict_scores = (const float*)d_in[0];
    const float* predict_points = (const float*)d_in[1];
    const int*   scores         = (const int*)d_in[2];
    const float* points         = (const float*)d_in[3];
    int* out = (int*)d_out;
    hipLaunchKernelGGL(hungarian_kernel, dim3(Bb), dim3(Tt), 0, stream,
                       predict_scores, predict_points, scores, points, out);
}